// Round 1
// baseline (132.868 us; speedup 1.0000x reference)
//
#include <hip/hip_runtime.h>

#define DEG 10
#define KK  11      // DEG+1 coefficients
#define DV  12      // number of variables
#define NP  66      // D*(D-1)/2 pairs
#define BLK 256

__device__ __constant__ float c_binom[KK] =
    {1.f, 10.f, 45.f, 120.f, 210.f, 252.f, 210.f, 120.f, 45.f, 10.f, 1.f};

__global__ __launch_bounds__(BLK)
void decor_kernel(const float* __restrict__ in,
                  const float* __restrict__ params,
                  const float* __restrict__ pr,
                  float* __restrict__ out,
                  int n)
{
    // params transposed to [pair][k], padded to 12 floats/row (48B, float4-aligned),
    // with binomial coefficients pre-folded.
    __shared__ float sp[NP][12];
    __shared__ float sa[DV];   // t = fma(x, sa[c], sb[c])
    __shared__ float sb[DV];

    const int tid = threadIdx.x;

    for (int i = tid; i < KK * NP; i += BLK) {
        int k = i / NP;
        int p = i - k * NP;
        sp[p][k] = params[i] * c_binom[k];
    }
    if (tid < NP) sp[tid][11] = 0.0f;   // pad lane (never used in math)
    if (tid < DV) {
        float low  = pr[tid];
        float high = pr[DV + tid];
        float w    = high - low;
        float lo   = low - 0.1f * w;
        float hi   = high + 0.1f * w;
        float inv  = 1.0f / (hi - lo);
        sa[tid] = inv;
        sb[tid] = -lo * inv;
    }
    __syncthreads();

    const int idx = blockIdx.x * BLK + tid;
    if (idx >= n) return;

    const float4* in4 = (const float4*)in;
    float4 r0 = in4[idx * 3 + 0];
    float4 r1 = in4[idx * 3 + 1];
    float4 r2 = in4[idx * 3 + 2];

    float x[DV];
    x[0] = r0.x; x[1] = r0.y; x[2]  = r0.z; x[3]  = r0.w;
    x[4] = r1.x; x[5] = r1.y; x[6]  = r1.z; x[7]  = r1.w;
    x[8] = r2.x; x[9] = r2.y; x[10] = r2.z; x[11] = r2.w;

    float acc[DV];
#pragma unroll
    for (int v = 0; v < DV; ++v) acc[v] = x[v];

#pragma unroll
    for (int c = 0; c < DV - 1; ++c) {
        // scaled coordinate for column c
        float t = __builtin_fmaf(x[c], sa[c], sb[c]);
        float u = 1.0f - t;

        // Bernstein basis (binom folded into params; x[c] folded into q-pass)
        float b[KK];
        b[0] = 1.0f;
#pragma unroll
        for (int k = 1; k < KK; ++k) b[k] = b[k - 1] * t;
        float q = x[c];                    // fold input[n,c] weight for free
#pragma unroll
        for (int k = KK - 1; k >= 0; --k) { b[k] *= q; q *= u; }

#pragma unroll
        for (int v = c + 1; v < DV; ++v) {
            const float* w = sp[v * (v - 1) / 2 + c];
            float4 w0 = *(const float4*)(w + 0);
            float4 w1 = *(const float4*)(w + 4);
            float4 w2 = *(const float4*)(w + 8);
            float a = acc[v];
            a = __builtin_fmaf(b[0],  w0.x, a);
            a = __builtin_fmaf(b[1],  w0.y, a);
            a = __builtin_fmaf(b[2],  w0.z, a);
            a = __builtin_fmaf(b[3],  w0.w, a);
            a = __builtin_fmaf(b[4],  w1.x, a);
            a = __builtin_fmaf(b[5],  w1.y, a);
            a = __builtin_fmaf(b[6],  w1.z, a);
            a = __builtin_fmaf(b[7],  w1.w, a);
            a = __builtin_fmaf(b[8],  w2.x, a);
            a = __builtin_fmaf(b[9],  w2.y, a);
            a = __builtin_fmaf(b[10], w2.z, a);
            acc[v] = a;
        }
    }

    float4 o0 = {acc[0], acc[1], acc[2],  acc[3]};
    float4 o1 = {acc[4], acc[5], acc[6],  acc[7]};
    float4 o2 = {acc[8], acc[9], acc[10], acc[11]};
    float4* out4 = (float4*)out;
    out4[idx * 3 + 0] = o0;
    out4[idx * 3 + 1] = o1;
    out4[idx * 3 + 2] = o2;
}

extern "C" void kernel_launch(void* const* d_in, const int* in_sizes, int n_in,
                              void* d_out, int out_size, void* d_ws, size_t ws_size,
                              hipStream_t stream)
{
    const float* in     = (const float*)d_in[0];   // [N, 12] fp32
    const float* params = (const float*)d_in[1];   // [11, 66] fp32
    const float* pr     = (const float*)d_in[2];   // [2, 12] fp32
    float* out          = (float*)d_out;           // [N, 12] fp32

    const int n = in_sizes[0] / DV;                // number of samples
    const int grid = (n + BLK - 1) / BLK;
    decor_kernel<<<grid, BLK, 0, stream>>>(in, params, pr, out, n);
}